// Round 1
// baseline (611.264 us; speedup 1.0000x reference)
//
#include <hip/hip_runtime.h>

#define F_DIM 128
#define H_DIM 16

// ---------------- degree / norm ----------------

__global__ void k_init_deg(float* __restrict__ deg, int n) {
    int i = blockIdx.x * blockDim.x + threadIdx.x;
    if (i < n) deg[i] = 1.0f;  // self-loop
}

__global__ void k_count_deg(const int* __restrict__ dst, float* __restrict__ deg, int e) {
    int i = blockIdx.x * blockDim.x + threadIdx.x;
    if (i < e) atomicAdd(&deg[dst[i]], 1.0f);
}

__global__ void k_finalize_dis(float* __restrict__ deg, int n) {
    int i = blockIdx.x * blockDim.x + threadIdx.x;
    if (i < n) deg[i] = rsqrtf(deg[i]);  // deg >= 1 always (self-loops)
}

// ---------------- layer 1: h1 = x @ W1 ; agg1 = b1 + h1*dis^2 (self-loop) ----------------

__global__ void k_gemm1(const float* __restrict__ x, const float* __restrict__ W1,
                        const float* __restrict__ b1, const float* __restrict__ dis,
                        float* __restrict__ h1, float* __restrict__ agg1, int n) {
    __shared__ float Ws[F_DIM * H_DIM];
    for (int t = threadIdx.x; t < F_DIM * H_DIM; t += blockDim.x) Ws[t] = W1[t];
    __syncthreads();
    int i = blockIdx.x * blockDim.x + threadIdx.x;
    if (i >= n) return;

    float acc[H_DIM];
#pragma unroll
    for (int j = 0; j < H_DIM; j++) acc[j] = 0.0f;

    const float4* xv = (const float4*)(x + (size_t)i * F_DIM);
#pragma unroll 4
    for (int k4 = 0; k4 < F_DIM / 4; k4++) {
        float4 v = xv[k4];
        int k = k4 * 4;
#pragma unroll
        for (int j = 0; j < H_DIM; j++) acc[j] += v.x * Ws[(k + 0) * H_DIM + j];
#pragma unroll
        for (int j = 0; j < H_DIM; j++) acc[j] += v.y * Ws[(k + 1) * H_DIM + j];
#pragma unroll
        for (int j = 0; j < H_DIM; j++) acc[j] += v.z * Ws[(k + 2) * H_DIM + j];
#pragma unroll
        for (int j = 0; j < H_DIM; j++) acc[j] += v.w * Ws[(k + 3) * H_DIM + j];
    }

    float d = dis[i];
    float d2 = d * d;
    float* h1p = h1 + (size_t)i * H_DIM;
    float* agp = agg1 + (size_t)i * H_DIM;
#pragma unroll
    for (int j = 0; j < H_DIM; j++) {
        h1p[j] = acc[j];
        agp[j] = b1[j] + acc[j] * d2;
    }
}

// ---------------- scatter 1: agg1[dst] += h1[src] * dis[src]*dis[dst] ----------------
// 16 threads per edge: coalesced-in-16 gather of h1 row, coalesced-in-16 atomics.

__global__ void k_scatter1(const int* __restrict__ src, const int* __restrict__ dst,
                           const float* __restrict__ dis, const float* __restrict__ h1,
                           float* __restrict__ agg1, int e) {
    long long tid = (long long)blockIdx.x * blockDim.x + threadIdx.x;
    if (tid >= (long long)e * H_DIM) return;
    int ei = (int)(tid >> 4);
    int j  = (int)(tid & (H_DIM - 1));
    int s = src[ei];
    int d = dst[ei];
    float w = dis[s] * dis[d];
    atomicAdd(&agg1[(size_t)d * H_DIM + j], h1[(size_t)s * H_DIM + j] * w);
}

// ---------------- layer 2: h2 = relu(agg1) @ W2 ; out = b2 + h2*dis^2 ----------------

__global__ void k_layer2(const float* __restrict__ agg1, const float* __restrict__ W2,
                         const float* __restrict__ b2, const float* __restrict__ dis,
                         float* __restrict__ h2, float* __restrict__ out, int n) {
    int i = blockIdx.x * blockDim.x + threadIdx.x;
    if (i >= n) return;
    const float4* ap = (const float4*)(agg1 + (size_t)i * H_DIM);
    float acc = 0.0f;
#pragma unroll
    for (int q = 0; q < H_DIM / 4; q++) {
        float4 v = ap[q];
        float w0 = W2[q * 4 + 0], w1 = W2[q * 4 + 1], w2 = W2[q * 4 + 2], w3 = W2[q * 4 + 3];
        acc += fmaxf(v.x, 0.0f) * w0;
        acc += fmaxf(v.y, 0.0f) * w1;
        acc += fmaxf(v.z, 0.0f) * w2;
        acc += fmaxf(v.w, 0.0f) * w3;
    }
    float d = dis[i];
    h2[i] = acc;
    out[i] = b2[0] + acc * d * d;
}

// ---------------- scatter 2: out[dst] += h2[src] * dis[src]*dis[dst] ----------------

__global__ void k_scatter2(const int* __restrict__ src, const int* __restrict__ dst,
                           const float* __restrict__ dis, const float* __restrict__ h2,
                           float* __restrict__ out, int e) {
    int ei = blockIdx.x * blockDim.x + threadIdx.x;
    if (ei >= e) return;
    int s = src[ei];
    int d = dst[ei];
    atomicAdd(&out[d], h2[s] * dis[s] * dis[d]);
}

extern "C" void kernel_launch(void* const* d_in, const int* in_sizes, int n_in,
                              void* d_out, int out_size, void* d_ws, size_t ws_size,
                              hipStream_t stream) {
    const float* x  = (const float*)d_in[0];
    const int*   ei = (const int*)d_in[1];
    const float* W1 = (const float*)d_in[2];
    const float* b1 = (const float*)d_in[3];
    const float* W2 = (const float*)d_in[4];
    const float* b2 = (const float*)d_in[5];

    const int n = in_sizes[0] / F_DIM;
    const int e = in_sizes[1] / 2;
    const int* src = ei;
    const int* dst = ei + e;

    float* ws   = (float*)d_ws;
    float* dis  = ws;                          // [n]
    float* h1   = dis + n;                     // [n*16]
    float* agg1 = h1 + (size_t)n * H_DIM;      // [n*16]
    float* h2   = agg1 + (size_t)n * H_DIM;    // [n]
    float* out  = (float*)d_out;               // [n]

    const int B = 256;
    k_init_deg<<<(n + B - 1) / B, B, 0, stream>>>(dis, n);
    k_count_deg<<<(e + B - 1) / B, B, 0, stream>>>(dst, dis, e);
    k_finalize_dis<<<(n + B - 1) / B, B, 0, stream>>>(dis, n);
    k_gemm1<<<(n + B - 1) / B, B, 0, stream>>>(x, W1, b1, dis, h1, agg1, n);
    long long tot = (long long)e * H_DIM;
    k_scatter1<<<(int)((tot + B - 1) / B), B, 0, stream>>>(src, dst, dis, h1, agg1, e);
    k_layer2<<<(n + B - 1) / B, B, 0, stream>>>(agg1, W2, b2, dis, h2, out, n);
    k_scatter2<<<(e + B - 1) / B, B, 0, stream>>>(src, dst, dis, h2, out, e);
}

// Round 3
// 579.193 us; speedup vs baseline: 1.0554x; 1.0554x over previous
//
#include <hip/hip_runtime.h>

#define F_DIM 128
#define H_DIM 16
#define NPB 128          // nodes per bucket (power of 2, dst>>7)
#define NPB_SHIFT 7
#define NB_MAX 1024      // max buckets supported (n <= 131072)
#define NBLK1 256        // blocks in bucketing pass
#define T1 1024          // threads in bucketing pass

// ---------------- phase 1a: per-block per-bucket edge counts ----------------
__global__ void k_count(const int* __restrict__ dst, int e, int* __restrict__ blk_cnt, int nb) {
    __shared__ int hist[NB_MAX];
    for (int t = threadIdx.x; t < nb; t += T1) hist[t] = 0;
    __syncthreads();
    int chunk = (e + NBLK1 - 1) / NBLK1;
    int lo = blockIdx.x * chunk;
    int hi = min(e, lo + chunk);
    for (int i = lo + threadIdx.x; i < hi; i += T1)
        atomicAdd(&hist[dst[i] >> NPB_SHIFT], 1);
    __syncthreads();
    for (int b = threadIdx.x; b < nb; b += T1)
        blk_cnt[b * NBLK1 + blockIdx.x] = hist[b];
}

// ---------------- phase 1b: bucket totals + exclusive starts ----------------
__global__ void k_scan(const int* __restrict__ blk_cnt, int* __restrict__ starts, int nb) {
    __shared__ int s[T1];
    int t = threadIdx.x;
    int c = 0;
    if (t < nb) {
        const int* row = blk_cnt + (size_t)t * NBLK1;
        for (int k = 0; k < NBLK1; k++) c += row[k];
    }
    s[t] = c;
    __syncthreads();
    for (int off = 1; off < T1; off <<= 1) {
        int u = (t >= off) ? s[t - off] : 0;
        __syncthreads();
        s[t] += u;
        __syncthreads();
    }
    if (t == 0) starts[0] = 0;
    if (t < nb) starts[t + 1] = s[t];  // inclusive -> starts
}

// ---------------- phase 1c: per-(bucket,block) bases, in place ----------------
__global__ void k_bases(int* __restrict__ blk_cnt, const int* __restrict__ starts) {
    __shared__ int s[NBLK1];
    int row = blockIdx.x;
    int t = threadIdx.x;
    int v = blk_cnt[row * NBLK1 + t];
    s[t] = v;
    __syncthreads();
    for (int off = 1; off < NBLK1; off <<= 1) {
        int u = (t >= off) ? s[t - off] : 0;
        __syncthreads();
        s[t] += u;
        __syncthreads();
    }
    blk_cnt[row * NBLK1 + t] = starts[row] + s[t] - v;  // exclusive + bucket start
}

// ---------------- phase 1d: place edges: packed = src | (dst_local<<17) ----------------
__global__ void k_place(const int* __restrict__ src, const int* __restrict__ dst, int e,
                        const int* __restrict__ bases, int* __restrict__ packed, int nb) {
    __shared__ int lcur[NB_MAX];
    for (int t = threadIdx.x; t < nb; t += T1) lcur[t] = 0;
    __syncthreads();
    int chunk = (e + NBLK1 - 1) / NBLK1;
    int lo = blockIdx.x * chunk;
    int hi = min(e, lo + chunk);
    for (int i = lo + threadIdx.x; i < hi; i += T1) {
        int d = dst[i];
        int b = d >> NPB_SHIFT;
        int dl = d & (NPB - 1);
        int pos = bases[b * NBLK1 + blockIdx.x] + atomicAdd(&lcur[b], 1);
        packed[pos] = src[i] | (dl << 17);
    }
}

// ---------------- degree -> dis = rsqrt(1 + indeg) ----------------
__global__ void k_deg(const int* __restrict__ packed, const int* __restrict__ starts,
                      float* __restrict__ dis, int n) {
    __shared__ int cnt[NPB];
    int b = blockIdx.x, t = threadIdx.x;
    if (t < NPB) cnt[t] = 0;
    __syncthreads();
    int lo = starts[b], hi = starts[b + 1];
    for (int i = lo + t; i < hi; i += blockDim.x)
        atomicAdd(&cnt[packed[i] >> 17], 1);
    __syncthreads();
    int i0 = b * NPB;
    int nloc = min(NPB, n - i0);
    if (t < nloc) dis[i0 + t] = rsqrtf(1.0f + (float)cnt[t]);
}

// ---------------- g = dis_i * (x_i @ W1) ----------------
__global__ void k_gemm1(const float* __restrict__ x, const float* __restrict__ W1,
                        const float* __restrict__ dis, float* __restrict__ g, int n) {
    __shared__ float Ws[F_DIM * H_DIM];
    for (int t = threadIdx.x; t < F_DIM * H_DIM; t += blockDim.x) Ws[t] = W1[t];
    __syncthreads();
    int i = blockIdx.x * blockDim.x + threadIdx.x;
    if (i >= n) return;

    float acc[H_DIM];
#pragma unroll
    for (int j = 0; j < H_DIM; j++) acc[j] = 0.0f;

    const float4* xv = (const float4*)(x + (size_t)i * F_DIM);
#pragma unroll 4
    for (int k4 = 0; k4 < F_DIM / 4; k4++) {
        float4 v = xv[k4];
        int k = k4 * 4;
#pragma unroll
        for (int j = 0; j < H_DIM; j++) acc[j] += v.x * Ws[(k + 0) * H_DIM + j];
#pragma unroll
        for (int j = 0; j < H_DIM; j++) acc[j] += v.y * Ws[(k + 1) * H_DIM + j];
#pragma unroll
        for (int j = 0; j < H_DIM; j++) acc[j] += v.z * Ws[(k + 2) * H_DIM + j];
#pragma unroll
        for (int j = 0; j < H_DIM; j++) acc[j] += v.w * Ws[(k + 3) * H_DIM + j];
    }
    float d = dis[i];
    float* gp = g + (size_t)i * H_DIM;
#pragma unroll
    for (int j = 0; j < H_DIM; j++) gp[j] = d * acc[j];
}

// ---- conv1 aggregate (bucket-local LDS) + relu + W2 -> g2 = dis * h2 ----
__global__ void k_p2(const int* __restrict__ packed, const int* __restrict__ starts,
                     const float* __restrict__ dis, const float* __restrict__ g,
                     const float* __restrict__ b1, const float* __restrict__ W2,
                     float* __restrict__ g2, int n) {
    __shared__ float agg[NPB * 17];
    __shared__ float dl_dis[NPB];
    int b = blockIdx.x, t = threadIdx.x;
    int i0 = b * NPB;
    int nloc = min(NPB, n - i0);
    if (t < nloc) dl_dis[t] = dis[i0 + t];
    __syncthreads();
    // self-loop init: agg[dl] = dis_i * g_i  (= dis_i^2 * h1_i)
    for (int idx = t; idx < nloc * H_DIM; idx += blockDim.x) {
        int dl = idx >> 4, j = idx & 15;
        agg[dl * 17 + j] = dl_dis[dl] * g[(size_t)(i0 + dl) * H_DIM + j];
    }
    __syncthreads();
    int lo = starts[b], hi = starts[b + 1];
    int j = t & 15;
    for (int i = lo + (t >> 4); i < hi; i += (int)(blockDim.x >> 4)) {
        int w = packed[i];
        int src = w & 0x1FFFF;
        int dl = w >> 17;
        atomicAdd(&agg[dl * 17 + j], g[(size_t)src * H_DIM + j] * dl_dis[dl]);
    }
    __syncthreads();
    if (t < nloc) {
        float acc = 0.0f;
#pragma unroll
        for (int q = 0; q < H_DIM; q++)
            acc += fmaxf(agg[t * 17 + q] + b1[q], 0.0f) * W2[q];
        g2[i0 + t] = dl_dis[t] * acc;
    }
}

// ---- conv2 aggregate (bucket-local LDS) -> out ----
// Convention: o accumulates raw g2 contributions (dis_src already inside g2);
// dis_dst applied EXACTLY ONCE in the epilogue. Self-loop init o=g2[i] matches.
__global__ void k_p3(const int* __restrict__ packed, const int* __restrict__ starts,
                     const float* __restrict__ dis, const float* __restrict__ g2,
                     const float* __restrict__ b2, float* __restrict__ out, int n) {
    __shared__ float o[NPB];
    __shared__ float dl_dis[NPB];
    int b = blockIdx.x, t = threadIdx.x;
    int i0 = b * NPB;
    int nloc = min(NPB, n - i0);
    if (t < nloc) {
        dl_dis[t] = dis[i0 + t];
        o[t] = g2[i0 + t];  // self-loop term (dis_i applied in epilogue)
    }
    __syncthreads();
    int lo = starts[b], hi = starts[b + 1];
    for (int i = lo + t; i < hi; i += blockDim.x) {
        int w = packed[i];
        int src = w & 0x1FFFF;
        atomicAdd(&o[w >> 17], g2[src]);
    }
    __syncthreads();
    if (t < nloc) out[i0 + t] = b2[0] + dl_dis[t] * o[t];
}

extern "C" void kernel_launch(void* const* d_in, const int* in_sizes, int n_in,
                              void* d_out, int out_size, void* d_ws, size_t ws_size,
                              hipStream_t stream) {
    const float* x  = (const float*)d_in[0];
    const int*   ei = (const int*)d_in[1];
    const float* W1 = (const float*)d_in[2];
    const float* b1 = (const float*)d_in[3];
    const float* W2 = (const float*)d_in[4];
    const float* b2 = (const float*)d_in[5];

    const int n = in_sizes[0] / F_DIM;
    const int e = in_sizes[1] / 2;
    const int* src = ei;
    const int* dst = ei + e;
    const int nb = (n + NPB - 1) / NPB;

    // workspace layout
    char* p = (char*)d_ws;
    float* dis    = (float*)p;               p += sizeof(float) * n;
    float* g      = (float*)p;               p += sizeof(float) * (size_t)n * H_DIM;
    float* g2     = (float*)p;               p += sizeof(float) * n;
    int*   packed = (int*)p;                 p += sizeof(int) * (size_t)e;
    int*   blk_cnt= (int*)p;                 p += sizeof(int) * (size_t)nb * NBLK1;
    int*   starts = (int*)p;                 p += sizeof(int) * (nb + 1);

    float* out = (float*)d_out;
    const int B = 256;

    k_count<<<NBLK1, T1, 0, stream>>>(dst, e, blk_cnt, nb);
    k_scan<<<1, T1, 0, stream>>>(blk_cnt, starts, nb);
    k_bases<<<nb, NBLK1, 0, stream>>>(blk_cnt, starts);
    k_place<<<NBLK1, T1, 0, stream>>>(src, dst, e, blk_cnt, packed, nb);
    k_deg<<<nb, B, 0, stream>>>(packed, starts, dis, n);
    k_gemm1<<<(n + B - 1) / B, B, 0, stream>>>(x, W1, dis, g, n);
    k_p2<<<nb, B, 0, stream>>>(packed, starts, dis, g, b1, W2, g2, n);
    k_p3<<<nb, B, 0, stream>>>(packed, starts, dis, g2, b2, out, n);
}

// Round 4
// 575.731 us; speedup vs baseline: 1.0617x; 1.0060x over previous
//
#include <hip/hip_runtime.h>

#define F_DIM 128
#define H_DIM 16
#define NPB 128          // nodes per bucket (power of 2, dst>>7)
#define NPB_SHIFT 7
#define NB_MAX 1024      // max buckets supported (n <= 131072)
#define NBLK1 256        // blocks in bucketing pass
#define T1 1024          // threads in bucketing pass

// ---------------- phase 1a: per-block per-bucket edge counts ----------------
__global__ void k_count(const int* __restrict__ dst, int e, int* __restrict__ blk_cnt, int nb) {
    __shared__ int hist[NB_MAX];
    for (int t = threadIdx.x; t < nb; t += T1) hist[t] = 0;
    __syncthreads();
    int chunk = (e + NBLK1 - 1) / NBLK1;
    int lo = blockIdx.x * chunk;
    int hi = min(e, lo + chunk);
    for (int i = lo + threadIdx.x; i < hi; i += T1)
        atomicAdd(&hist[dst[i] >> NPB_SHIFT], 1);
    __syncthreads();
    for (int b = threadIdx.x; b < nb; b += T1)
        blk_cnt[b * NBLK1 + blockIdx.x] = hist[b];
}

// ---------------- phase 1b: bucket totals + exclusive starts ----------------
__global__ void k_scan(const int* __restrict__ blk_cnt, int* __restrict__ starts, int nb) {
    __shared__ int s[T1];
    int t = threadIdx.x;
    int c = 0;
    if (t < nb) {
        const int* row = blk_cnt + (size_t)t * NBLK1;
        for (int k = 0; k < NBLK1; k++) c += row[k];
    }
    s[t] = c;
    __syncthreads();
    for (int off = 1; off < T1; off <<= 1) {
        int u = (t >= off) ? s[t - off] : 0;
        __syncthreads();
        s[t] += u;
        __syncthreads();
    }
    if (t == 0) starts[0] = 0;
    if (t < nb) starts[t + 1] = s[t];  // inclusive -> starts
}

// ---------------- phase 1c: per-(bucket,block) bases, in place ----------------
__global__ void k_bases(int* __restrict__ blk_cnt, const int* __restrict__ starts) {
    __shared__ int s[NBLK1];
    int row = blockIdx.x;
    int t = threadIdx.x;
    int v = blk_cnt[row * NBLK1 + t];
    s[t] = v;
    __syncthreads();
    for (int off = 1; off < NBLK1; off <<= 1) {
        int u = (t >= off) ? s[t - off] : 0;
        __syncthreads();
        s[t] += u;
        __syncthreads();
    }
    blk_cnt[row * NBLK1 + t] = starts[row] + s[t] - v;  // exclusive + bucket start
}

// ---------------- phase 1d: place edges: packed = src | (dst_local<<17) ----------------
__global__ void k_place(const int* __restrict__ src, const int* __restrict__ dst, int e,
                        const int* __restrict__ bases, int* __restrict__ packed, int nb) {
    __shared__ int lcur[NB_MAX];
    for (int t = threadIdx.x; t < nb; t += T1) lcur[t] = 0;
    __syncthreads();
    int chunk = (e + NBLK1 - 1) / NBLK1;
    int lo = blockIdx.x * chunk;
    int hi = min(e, lo + chunk);
    for (int i = lo + threadIdx.x; i < hi; i += T1) {
        int d = dst[i];
        int b = d >> NPB_SHIFT;
        int dl = d & (NPB - 1);
        int pos = bases[b * NBLK1 + blockIdx.x] + atomicAdd(&lcur[b], 1);
        packed[pos] = src[i] | (dl << 17);
    }
}

// ---------------- degree -> dis = rsqrt(1 + indeg) ----------------
__global__ void k_deg(const int* __restrict__ packed, const int* __restrict__ starts,
                      float* __restrict__ dis, int n) {
    __shared__ int cnt[NPB];
    int b = blockIdx.x, t = threadIdx.x;
    if (t < NPB) cnt[t] = 0;
    __syncthreads();
    int lo = starts[b], hi = starts[b + 1];
    for (int i = lo + t; i < hi; i += blockDim.x)
        atomicAdd(&cnt[packed[i] >> 17], 1);
    __syncthreads();
    int i0 = b * NPB;
    int nloc = min(NPB, n - i0);
    if (t < nloc) dis[i0 + t] = rsqrtf(1.0f + (float)cnt[t]);
}

// ---------------- g = dis_i * (x_i @ W1) ----------------
__global__ void k_gemm1(const float* __restrict__ x, const float* __restrict__ W1,
                        const float* __restrict__ dis, float* __restrict__ g, int n) {
    __shared__ float Ws[F_DIM * H_DIM];
    for (int t = threadIdx.x; t < F_DIM * H_DIM; t += blockDim.x) Ws[t] = W1[t];
    __syncthreads();
    int i = blockIdx.x * blockDim.x + threadIdx.x;
    if (i >= n) return;

    float acc[H_DIM];
#pragma unroll
    for (int j = 0; j < H_DIM; j++) acc[j] = 0.0f;

    const float4* xv = (const float4*)(x + (size_t)i * F_DIM);
#pragma unroll 4
    for (int k4 = 0; k4 < F_DIM / 4; k4++) {
        float4 v = xv[k4];
        int k = k4 * 4;
#pragma unroll
        for (int j = 0; j < H_DIM; j++) acc[j] += v.x * Ws[(k + 0) * H_DIM + j];
#pragma unroll
        for (int j = 0; j < H_DIM; j++) acc[j] += v.y * Ws[(k + 1) * H_DIM + j];
#pragma unroll
        for (int j = 0; j < H_DIM; j++) acc[j] += v.z * Ws[(k + 2) * H_DIM + j];
#pragma unroll
        for (int j = 0; j < H_DIM; j++) acc[j] += v.w * Ws[(k + 3) * H_DIM + j];
    }
    float d = dis[i];
    float* gp = g + (size_t)i * H_DIM;
#pragma unroll
    for (int j = 0; j < H_DIM; j++) gp[j] = d * acc[j];
}

// ---- conv1 aggregate (bucket-local LDS) + relu + W2 -> g2 = dis * h2 ----
// One thread per edge, 4 edges per iteration: 16 independent float4 gathers
// issued before any LDS atomic -> 256 cache lines in flight per wave.
__global__ __launch_bounds__(256) void k_p2(
        const int* __restrict__ packed, const int* __restrict__ starts,
        const float* __restrict__ dis, const float* __restrict__ g,
        const float* __restrict__ b1, const float* __restrict__ W2,
        float* __restrict__ g2, int n) {
    __shared__ float agg[NPB * 17];
    __shared__ float dl_dis[NPB];
    int b = blockIdx.x, t = threadIdx.x;
    int i0 = b * NPB;
    int nloc = min(NPB, n - i0);
    if (t < nloc) dl_dis[t] = dis[i0 + t];
    __syncthreads();
    // self-loop init: agg[dl] = dis_i * g_i  (= dis_i^2 * h1_i)
    for (int idx = t; idx < nloc * H_DIM; idx += blockDim.x) {
        int dl = idx >> 4, j = idx & 15;
        agg[dl * 17 + j] = dl_dis[dl] * g[(size_t)(i0 + dl) * H_DIM + j];
    }
    __syncthreads();

    const float4* gv = (const float4*)g;  // row i -> gv[4i .. 4i+3]
    int lo = starts[b], hi = starts[b + 1];
    for (int base = lo + t; base < hi; base += 256 * 4) {
        int e0 = base;
        int e1 = base + 256, e2 = base + 512, e3 = base + 768;
        bool v1 = e1 < hi, v2 = e2 < hi, v3 = e3 < hi;
        int last = hi - 1;
        int w0 = packed[e0];
        int w1 = packed[v1 ? e1 : last];
        int w2 = packed[v2 ? e2 : last];
        int w3 = packed[v3 ? e3 : last];
        int s0 = w0 & 0x1FFFF, d0 = w0 >> 17;
        int s1 = w1 & 0x1FFFF, d1 = w1 >> 17;
        int s2 = w2 & 0x1FFFF, d2 = w2 >> 17;
        int s3 = w3 & 0x1FFFF, d3 = w3 >> 17;
        float c0 = dl_dis[d0];
        float c1 = v1 ? dl_dis[d1] : 0.0f;
        float c2 = v2 ? dl_dis[d2] : 0.0f;
        float c3 = v3 ? dl_dis[d3] : 0.0f;
        // issue all 16 row-loads before consuming any
        float4 r0[4], r1[4], r2[4], r3[4];
#pragma unroll
        for (int q = 0; q < 4; q++) r0[q] = gv[(size_t)s0 * 4 + q];
#pragma unroll
        for (int q = 0; q < 4; q++) r1[q] = gv[(size_t)s1 * 4 + q];
#pragma unroll
        for (int q = 0; q < 4; q++) r2[q] = gv[(size_t)s2 * 4 + q];
#pragma unroll
        for (int q = 0; q < 4; q++) r3[q] = gv[(size_t)s3 * 4 + q];
#pragma unroll
        for (int q = 0; q < 4; q++) {
            atomicAdd(&agg[d0 * 17 + 4 * q + 0], r0[q].x * c0);
            atomicAdd(&agg[d0 * 17 + 4 * q + 1], r0[q].y * c0);
            atomicAdd(&agg[d0 * 17 + 4 * q + 2], r0[q].z * c0);
            atomicAdd(&agg[d0 * 17 + 4 * q + 3], r0[q].w * c0);
        }
#pragma unroll
        for (int q = 0; q < 4; q++) {
            atomicAdd(&agg[d1 * 17 + 4 * q + 0], r1[q].x * c1);
            atomicAdd(&agg[d1 * 17 + 4 * q + 1], r1[q].y * c1);
            atomicAdd(&agg[d1 * 17 + 4 * q + 2], r1[q].z * c1);
            atomicAdd(&agg[d1 * 17 + 4 * q + 3], r1[q].w * c1);
        }
#pragma unroll
        for (int q = 0; q < 4; q++) {
            atomicAdd(&agg[d2 * 17 + 4 * q + 0], r2[q].x * c2);
            atomicAdd(&agg[d2 * 17 + 4 * q + 1], r2[q].y * c2);
            atomicAdd(&agg[d2 * 17 + 4 * q + 2], r2[q].z * c2);
            atomicAdd(&agg[d2 * 17 + 4 * q + 3], r2[q].w * c2);
        }
#pragma unroll
        for (int q = 0; q < 4; q++) {
            atomicAdd(&agg[d3 * 17 + 4 * q + 0], r3[q].x * c3);
            atomicAdd(&agg[d3 * 17 + 4 * q + 1], r3[q].y * c3);
            atomicAdd(&agg[d3 * 17 + 4 * q + 2], r3[q].z * c3);
            atomicAdd(&agg[d3 * 17 + 4 * q + 3], r3[q].w * c3);
        }
    }
    __syncthreads();
    if (t < nloc) {
        float acc = 0.0f;
#pragma unroll
        for (int q = 0; q < H_DIM; q++)
            acc += fmaxf(agg[t * 17 + q] + b1[q], 0.0f) * W2[q];
        g2[i0 + t] = dl_dis[t] * acc;
    }
}

// ---- conv2 aggregate (bucket-local LDS) -> out ----
// 8 edges per thread per iteration, scalar gathers batched for MLP.
__global__ __launch_bounds__(256) void k_p3(
        const int* __restrict__ packed, const int* __restrict__ starts,
        const float* __restrict__ dis, const float* __restrict__ g2,
        const float* __restrict__ b2, float* __restrict__ out, int n) {
    __shared__ float o[NPB];
    __shared__ float dl_dis[NPB];
    int b = blockIdx.x, t = threadIdx.x;
    int i0 = b * NPB;
    int nloc = min(NPB, n - i0);
    if (t < nloc) {
        dl_dis[t] = dis[i0 + t];
        o[t] = g2[i0 + t];  // self-loop term (dis_i applied in epilogue)
    }
    __syncthreads();
    int lo = starts[b], hi = starts[b + 1];
    int last = hi - 1;
    for (int base = lo + t; base < hi; base += 256 * 8) {
        int w[8];
        float val[8];
        bool v[8];
#pragma unroll
        for (int k = 0; k < 8; k++) {
            int ei = base + 256 * k;
            v[k] = ei < hi;
            w[k] = packed[v[k] ? ei : last];
        }
#pragma unroll
        for (int k = 0; k < 8; k++) val[k] = g2[w[k] & 0x1FFFF];
#pragma unroll
        for (int k = 0; k < 8; k++)
            atomicAdd(&o[w[k] >> 17], v[k] ? val[k] : 0.0f);
    }
    __syncthreads();
    if (t < nloc) out[i0 + t] = b2[0] + dl_dis[t] * o[t];
}

extern "C" void kernel_launch(void* const* d_in, const int* in_sizes, int n_in,
                              void* d_out, int out_size, void* d_ws, size_t ws_size,
                              hipStream_t stream) {
    const float* x  = (const float*)d_in[0];
    const int*   ei = (const int*)d_in[1];
    const float* W1 = (const float*)d_in[2];
    const float* b1 = (const float*)d_in[3];
    const float* W2 = (const float*)d_in[4];
    const float* b2 = (const float*)d_in[5];

    const int n = in_sizes[0] / F_DIM;
    const int e = in_sizes[1] / 2;
    const int* src = ei;
    const int* dst = ei + e;
    const int nb = (n + NPB - 1) / NPB;

    // workspace layout
    char* p = (char*)d_ws;
    float* dis    = (float*)p;               p += sizeof(float) * n;
    float* g      = (float*)p;               p += sizeof(float) * (size_t)n * H_DIM;
    float* g2     = (float*)p;               p += sizeof(float) * n;
    int*   packed = (int*)p;                 p += sizeof(int) * (size_t)e;
    int*   blk_cnt= (int*)p;                 p += sizeof(int) * (size_t)nb * NBLK1;
    int*   starts = (int*)p;                 p += sizeof(int) * (nb + 1);

    float* out = (float*)d_out;
    const int B = 256;

    k_count<<<NBLK1, T1, 0, stream>>>(dst, e, blk_cnt, nb);
    k_scan<<<1, T1, 0, stream>>>(blk_cnt, starts, nb);
    k_bases<<<nb, NBLK1, 0, stream>>>(blk_cnt, starts);
    k_place<<<NBLK1, T1, 0, stream>>>(src, dst, e, blk_cnt, packed, nb);
    k_deg<<<nb, B, 0, stream>>>(packed, starts, dis, n);
    k_gemm1<<<(n + B - 1) / B, B, 0, stream>>>(x, W1, dis, g, n);
    k_p2<<<nb, B, 0, stream>>>(packed, starts, dis, g, b1, W2, g2, n);
    k_p3<<<nb, B, 0, stream>>>(packed, starts, dis, g2, b2, out, n);
}

// Round 5
// 557.055 us; speedup vs baseline: 1.0973x; 1.0335x over previous
//
#include <hip/hip_runtime.h>
#include <hip/hip_fp16.h>

#define F_DIM 128
#define H_DIM 16
#define NPB 128          // nodes per bucket (power of 2, dst>>7)
#define NPB_SHIFT 7
#define NB_MAX 1024      // max buckets supported (n <= 131072)
#define NBLK1 256        // blocks in bucketing pass
#define T1 1024          // threads in bucketing pass
#define SPLIT 4          // segment-blocks per bucket for edge kernels

struct __align__(8) h4 { __half2 a, b; };  // 4 halves, one dwordx2

// ---------------- phase 1a: per-block per-bucket edge counts ----------------
__global__ void k_count(const int* __restrict__ dst, int e, int* __restrict__ blk_cnt, int nb) {
    __shared__ int hist[NB_MAX];
    for (int t = threadIdx.x; t < nb; t += T1) hist[t] = 0;
    __syncthreads();
    int chunk = (e + NBLK1 - 1) / NBLK1;
    int lo = blockIdx.x * chunk;
    int hi = min(e, lo + chunk);
    for (int i = lo + threadIdx.x; i < hi; i += T1)
        atomicAdd(&hist[dst[i] >> NPB_SHIFT], 1);
    __syncthreads();
    for (int b = threadIdx.x; b < nb; b += T1)
        blk_cnt[b * NBLK1 + blockIdx.x] = hist[b];
}

// ---------------- phase 1b: bucket totals + exclusive starts ----------------
__global__ void k_scan(const int* __restrict__ blk_cnt, int* __restrict__ starts, int nb) {
    __shared__ int s[T1];
    int t = threadIdx.x;
    int c = 0;
    if (t < nb) {
        const int* row = blk_cnt + (size_t)t * NBLK1;
        for (int k = 0; k < NBLK1; k++) c += row[k];
    }
    s[t] = c;
    __syncthreads();
    for (int off = 1; off < T1; off <<= 1) {
        int u = (t >= off) ? s[t - off] : 0;
        __syncthreads();
        s[t] += u;
        __syncthreads();
    }
    if (t == 0) starts[0] = 0;
    if (t < nb) starts[t + 1] = s[t];
}

// ---------------- phase 1c: per-(bucket,block) bases, in place ----------------
__global__ void k_bases(int* __restrict__ blk_cnt, const int* __restrict__ starts) {
    __shared__ int s[NBLK1];
    int row = blockIdx.x;
    int t = threadIdx.x;
    int v = blk_cnt[row * NBLK1 + t];
    s[t] = v;
    __syncthreads();
    for (int off = 1; off < NBLK1; off <<= 1) {
        int u = (t >= off) ? s[t - off] : 0;
        __syncthreads();
        s[t] += u;
        __syncthreads();
    }
    blk_cnt[row * NBLK1 + t] = starts[row] + s[t] - v;
}

// ---------------- phase 1d: place edges: packed = src | (dst_local<<17) ----------------
__global__ void k_place(const int* __restrict__ src, const int* __restrict__ dst, int e,
                        const int* __restrict__ bases, int* __restrict__ packed, int nb) {
    __shared__ int lcur[NB_MAX];
    for (int t = threadIdx.x; t < nb; t += T1) lcur[t] = 0;
    __syncthreads();
    int chunk = (e + NBLK1 - 1) / NBLK1;
    int lo = blockIdx.x * chunk;
    int hi = min(e, lo + chunk);
    for (int i = lo + threadIdx.x; i < hi; i += T1) {
        int d = dst[i];
        int b = d >> NPB_SHIFT;
        int dl = d & (NPB - 1);
        int pos = bases[b * NBLK1 + blockIdx.x] + atomicAdd(&lcur[b], 1);
        packed[pos] = src[i] | (dl << 17);
    }
}

// ---------------- degree accumulation (split, LDS-local then coalesced atomic) ----------
__global__ __launch_bounds__(256) void k_degA(const int* __restrict__ packed,
                                              const int* __restrict__ starts,
                                              int* __restrict__ deg, int n) {
    __shared__ int cnt[NPB];
    int b = blockIdx.x >> 2, seg = blockIdx.x & (SPLIT - 1), t = threadIdx.x;
    if (t < NPB) cnt[t] = 0;
    __syncthreads();
    int lo0 = starts[b], hi0 = starts[b + 1], len = hi0 - lo0;
    int slo = lo0 + ((len * seg) >> 2);
    int shi = lo0 + ((len * (seg + 1)) >> 2);
    for (int base = slo + t; base < shi; base += 256 * 8) {
#pragma unroll
        for (int k = 0; k < 8; k++) {
            int e = base + 256 * k;
            if (e < shi) atomicAdd(&cnt[packed[e] >> 17], 1);
        }
    }
    __syncthreads();
    int i0 = b * NPB;
    int nloc = min(NPB, n - i0);
    if (t < nloc && cnt[t]) atomicAdd(&deg[i0 + t], cnt[t]);
}

// ---- g = dis_i*(x_i@W1): write fp16 copy (gather source) + fp32 self-loop init + dis ----
__global__ void k_gemm1(const float* __restrict__ x, const float* __restrict__ W1,
                        const int* __restrict__ deg, float* __restrict__ dis,
                        __half* __restrict__ gh, float* __restrict__ aggf, int n) {
    __shared__ float Ws[F_DIM * H_DIM];
    for (int t = threadIdx.x; t < F_DIM * H_DIM; t += blockDim.x) Ws[t] = W1[t];
    __syncthreads();
    int i = blockIdx.x * blockDim.x + threadIdx.x;
    if (i >= n) return;

    float acc[H_DIM];
#pragma unroll
    for (int j = 0; j < H_DIM; j++) acc[j] = 0.0f;

    const float4* xv = (const float4*)(x + (size_t)i * F_DIM);
#pragma unroll 4
    for (int k4 = 0; k4 < F_DIM / 4; k4++) {
        float4 v = xv[k4];
        int k = k4 * 4;
#pragma unroll
        for (int j = 0; j < H_DIM; j++) acc[j] += v.x * Ws[(k + 0) * H_DIM + j];
#pragma unroll
        for (int j = 0; j < H_DIM; j++) acc[j] += v.y * Ws[(k + 1) * H_DIM + j];
#pragma unroll
        for (int j = 0; j < H_DIM; j++) acc[j] += v.z * Ws[(k + 2) * H_DIM + j];
#pragma unroll
        for (int j = 0; j < H_DIM; j++) acc[j] += v.w * Ws[(k + 3) * H_DIM + j];
    }
    float d = rsqrtf(1.0f + (float)deg[i]);
    dis[i] = d;
    float* ap = aggf + ((size_t)i << 4);
    __half2* hp = (__half2*)(gh + ((size_t)i << 4));
#pragma unroll
    for (int p = 0; p < 8; p++) {
        float g0 = d * acc[2 * p];
        float g1 = d * acc[2 * p + 1];
        ap[2 * p] = g0;
        ap[2 * p + 1] = g1;
        hp[p] = __floats2half2_rn(g0, g1);
    }
}

// ---- conv1 edge aggregation: 4 lanes/edge, batch 4 -> 64 rows in flight/wave ----
// Accumulates RAW sum of g_src rows (dis_dst applied in k_p2e).
__global__ __launch_bounds__(256) void k_p2(const int* __restrict__ packed,
                                            const int* __restrict__ starts,
                                            const __half* __restrict__ gh,
                                            float* __restrict__ aggf, int n) {
    __shared__ float agg[NPB * 17];
    int b = blockIdx.x >> 2, seg = blockIdx.x & (SPLIT - 1), t = threadIdx.x;
    for (int idx = t; idx < NPB * 17; idx += 256) agg[idx] = 0.0f;
    __syncthreads();
    int lo0 = starts[b], hi0 = starts[b + 1], len = hi0 - lo0;
    int slo = lo0 + ((len * seg) >> 2);
    int shi = lo0 + ((len * (seg + 1)) >> 2);
    int egrp = t >> 2;       // 0..63: edge within 256-edge chunk
    int c = t & 3;           // dim quad: dims 4c..4c+3
    for (int base = slo; base < shi; base += 256) {
        h4 u[4]; int dl[4]; bool ok[4];
#pragma unroll
        for (int k = 0; k < 4; k++) {
            int e = base + 64 * k + egrp;
            ok[k] = e < shi;
            int w = packed[ok[k] ? e : slo];
            dl[k] = w >> 17;
            int s = w & 0x1FFFF;
            u[k] = *(const h4*)(gh + (((size_t)s) << 4) + (c << 2));
        }
#pragma unroll
        for (int k = 0; k < 4; k++) {
            float2 f0 = __half22float2(u[k].a);
            float2 f1 = __half22float2(u[k].b);
            float m = ok[k] ? 1.0f : 0.0f;
            int ad = dl[k] * 17 + (c << 2);
            atomicAdd(&agg[ad + 0], f0.x * m);
            atomicAdd(&agg[ad + 1], f0.y * m);
            atomicAdd(&agg[ad + 2], f1.x * m);
            atomicAdd(&agg[ad + 3], f1.y * m);
        }
    }
    __syncthreads();
    int i0 = b * NPB;
    int nloc = min(NPB, n - i0);
    for (int idx = t; idx < nloc * 16; idx += 256) {
        int dl = idx >> 4, j = idx & 15;
        atomicAdd(&aggf[(((size_t)(i0 + dl)) << 4) + j], agg[dl * 17 + j]);
    }
}

// ---- conv1 epilogue: h2 = relu(dis*agg + b1)@W2 ; g2 = dis*h2 ; seed conv2 self-loop ----
__global__ void k_p2e(const float* __restrict__ aggf, const float* __restrict__ dis,
                      const float* __restrict__ b1, const float* __restrict__ W2,
                      float* __restrict__ g2, float* __restrict__ o_glob, int n) {
    int i = blockIdx.x * blockDim.x + threadIdx.x;
    if (i >= n) return;
    float d = dis[i];
    const float4* ap = (const float4*)(aggf + ((size_t)i << 4));
    float acc = 0.0f;
#pragma unroll
    for (int q = 0; q < 4; q++) {
        float4 v = ap[q];
        acc += fmaxf(fmaf(d, v.x, b1[4 * q + 0]), 0.0f) * W2[4 * q + 0];
        acc += fmaxf(fmaf(d, v.y, b1[4 * q + 1]), 0.0f) * W2[4 * q + 1];
        acc += fmaxf(fmaf(d, v.z, b1[4 * q + 2]), 0.0f) * W2[4 * q + 2];
        acc += fmaxf(fmaf(d, v.w, b1[4 * q + 3]), 0.0f) * W2[4 * q + 3];
    }
    float g2v = d * acc;
    g2[i] = g2v;
    o_glob[i] = g2v;  // conv2 self-loop seed (dis applied in k_out)
}

// ---- conv2 edge aggregation (split, batch-8 scalar gathers, LDS sums) ----
__global__ __launch_bounds__(256) void k_p3(const int* __restrict__ packed,
                                            const int* __restrict__ starts,
                                            const float* __restrict__ g2,
                                            float* __restrict__ o_glob, int n) {
    __shared__ float o[NPB];
    int b = blockIdx.x >> 2, seg = blockIdx.x & (SPLIT - 1), t = threadIdx.x;
    if (t < NPB) o[t] = 0.0f;
    __syncthreads();
    int lo0 = starts[b], hi0 = starts[b + 1], len = hi0 - lo0;
    int slo = lo0 + ((len * seg) >> 2);
    int shi = lo0 + ((len * (seg + 1)) >> 2);
    for (int base = slo + t; base < shi; base += 256 * 8) {
        int w[8]; float v[8]; bool ok[8];
#pragma unroll
        for (int k = 0; k < 8; k++) {
            int e = base + 256 * k;
            ok[k] = e < shi;
            w[k] = packed[ok[k] ? e : slo];
        }
#pragma unroll
        for (int k = 0; k < 8; k++) v[k] = g2[w[k] & 0x1FFFF];
#pragma unroll
        for (int k = 0; k < 8; k++)
            atomicAdd(&o[w[k] >> 17], ok[k] ? v[k] : 0.0f);
    }
    __syncthreads();
    int i0 = b * NPB;
    int nloc = min(NPB, n - i0);
    if (t < nloc) atomicAdd(&o_glob[i0 + t], o[t]);
}

// ---- final: out = b2 + dis * (sum g2 + self) ----
__global__ void k_out(const float* __restrict__ o_glob, const float* __restrict__ dis,
                      const float* __restrict__ b2, float* __restrict__ out, int n) {
    int i = blockIdx.x * blockDim.x + threadIdx.x;
    if (i < n) out[i] = b2[0] + dis[i] * o_glob[i];
}

extern "C" void kernel_launch(void* const* d_in, const int* in_sizes, int n_in,
                              void* d_out, int out_size, void* d_ws, size_t ws_size,
                              hipStream_t stream) {
    const float* x  = (const float*)d_in[0];
    const int*   ei = (const int*)d_in[1];
    const float* W1 = (const float*)d_in[2];
    const float* b1 = (const float*)d_in[3];
    const float* W2 = (const float*)d_in[4];
    const float* b2 = (const float*)d_in[5];

    const int n = in_sizes[0] / F_DIM;
    const int e = in_sizes[1] / 2;
    const int* src = ei;
    const int* dst = ei + e;
    const int nb = (n + NPB - 1) / NPB;

    // workspace layout (base assumed 256B-aligned)
    char* p = (char*)d_ws;
    float* dis    = (float*)p;  p += sizeof(float) * n;
    int*   deg    = (int*)p;    p += sizeof(int) * n;
    float* g2     = (float*)p;  p += sizeof(float) * n;
    float* o_glob = (float*)p;  p += sizeof(float) * n;
    __half* gh    = (__half*)p; p += sizeof(__half) * (size_t)n * H_DIM;
    float* aggf   = (float*)p;  p += sizeof(float) * (size_t)n * H_DIM;
    int*   packed = (int*)p;    p += sizeof(int) * (size_t)e;
    int*   blk_cnt= (int*)p;    p += sizeof(int) * (size_t)nb * NBLK1;
    int*   starts = (int*)p;    p += sizeof(int) * (nb + 1);

    float* out = (float*)d_out;
    const int B = 256;
    const int gn = (n + B - 1) / B;

    hipMemsetAsync(deg, 0, sizeof(int) * n, stream);
    k_count<<<NBLK1, T1, 0, stream>>>(dst, e, blk_cnt, nb);
    k_scan<<<1, T1, 0, stream>>>(blk_cnt, starts, nb);
    k_bases<<<nb, NBLK1, 0, stream>>>(blk_cnt, starts);
    k_place<<<NBLK1, T1, 0, stream>>>(src, dst, e, blk_cnt, packed, nb);
    k_degA<<<nb * SPLIT, B, 0, stream>>>(packed, starts, deg, n);
    k_gemm1<<<gn, B, 0, stream>>>(x, W1, deg, dis, gh, aggf, n);
    k_p2<<<nb * SPLIT, B, 0, stream>>>(packed, starts, gh, aggf, n);
    k_p2e<<<gn, B, 0, stream>>>(aggf, dis, b1, W2, g2, o_glob, n);
    k_p3<<<nb * SPLIT, B, 0, stream>>>(packed, starts, g2, o_glob, n);
    k_out<<<gn, B, 0, stream>>>(o_glob, dis, b2, out, n);
}

// Round 6
// 260.320 us; speedup vs baseline: 2.3481x; 2.1399x over previous
//
#include <hip/hip_runtime.h>
#include <hip/hip_fp16.h>

#define F_DIM 128
#define H_DIM 16
#define NPB 128          // nodes per bucket (power of 2, dst>>7)
#define NPB_SHIFT 7
#define NB_MAX 1024      // max buckets supported (n <= 131072)
#define NBLK1 256        // blocks in bucketing pass
#define T1 1024          // threads in bucketing pass

struct __align__(8) h4 { __half2 a, b; };  // 4 halves, one dwordx2

// ---------------- phase 1a: per-block per-bucket edge counts ----------------
__global__ void k_count(const int* __restrict__ dst, int e, int* __restrict__ blk_cnt, int nb) {
    __shared__ int hist[NB_MAX];
    for (int t = threadIdx.x; t < nb; t += T1) hist[t] = 0;
    __syncthreads();
    int chunk = (e + NBLK1 - 1) / NBLK1;
    int lo = blockIdx.x * chunk;
    int hi = min(e, lo + chunk);
    for (int i = lo + threadIdx.x; i < hi; i += T1)
        atomicAdd(&hist[dst[i] >> NPB_SHIFT], 1);
    __syncthreads();
    for (int b = threadIdx.x; b < nb; b += T1)
        blk_cnt[b * NBLK1 + blockIdx.x] = hist[b];
}

// ---------------- phase 1b: bucket totals + exclusive starts ----------------
__global__ void k_scan(const int* __restrict__ blk_cnt, int* __restrict__ starts, int nb) {
    __shared__ int s[T1];
    int t = threadIdx.x;
    int c = 0;
    if (t < nb) {
        const int* row = blk_cnt + (size_t)t * NBLK1;
        for (int k = 0; k < NBLK1; k++) c += row[k];
    }
    s[t] = c;
    __syncthreads();
    for (int off = 1; off < T1; off <<= 1) {
        int u = (t >= off) ? s[t - off] : 0;
        __syncthreads();
        s[t] += u;
        __syncthreads();
    }
    if (t == 0) starts[0] = 0;
    if (t < nb) starts[t + 1] = s[t];
}

// ---------------- phase 1c: per-(bucket,block) bases, in place ----------------
__global__ void k_bases(int* __restrict__ blk_cnt, const int* __restrict__ starts) {
    __shared__ int s[NBLK1];
    int row = blockIdx.x;
    int t = threadIdx.x;
    int v = blk_cnt[row * NBLK1 + t];
    s[t] = v;
    __syncthreads();
    for (int off = 1; off < NBLK1; off <<= 1) {
        int u = (t >= off) ? s[t - off] : 0;
        __syncthreads();
        s[t] += u;
        __syncthreads();
    }
    blk_cnt[row * NBLK1 + t] = starts[row] + s[t] - v;
}

// ---------------- phase 1d: place edges: packed = src | (dst_local<<17) ----------------
__global__ void k_place(const int* __restrict__ src, const int* __restrict__ dst, int e,
                        const int* __restrict__ bases, int* __restrict__ packed, int nb) {
    __shared__ int lcur[NB_MAX];
    for (int t = threadIdx.x; t < nb; t += T1) lcur[t] = 0;
    __syncthreads();
    int chunk = (e + NBLK1 - 1) / NBLK1;
    int lo = blockIdx.x * chunk;
    int hi = min(e, lo + chunk);
    for (int i = lo + threadIdx.x; i < hi; i += T1) {
        int d = dst[i];
        int b = d >> NPB_SHIFT;
        int dl = d & (NPB - 1);
        int pos = bases[b * NBLK1 + blockIdx.x] + atomicAdd(&lcur[b], 1);
        packed[pos] = src[i] | (dl << 17);
    }
}

// ---- phase 2: within-bucket counting sort by dst -> full CSR + dis + rowp ----
// Only INT LDS atomics (native ds_add_u32).
__global__ __launch_bounds__(256) void k_sort(
        const int* __restrict__ packed, const int* __restrict__ starts,
        int* __restrict__ col, int* __restrict__ rowp, float* __restrict__ dis,
        int n, int nb) {
    __shared__ int cnt[NPB];
    __shared__ int scan_s[NPB];
    __shared__ int base_s[NPB];
    int b = blockIdx.x, t = threadIdx.x;
    if (t < NPB) cnt[t] = 0;
    __syncthreads();
    int lo = starts[b], hi = starts[b + 1];
    for (int e = lo + t; e < hi; e += 256)
        atomicAdd(&cnt[packed[e] >> 17], 1);
    __syncthreads();
    if (t < NPB) scan_s[t] = cnt[t];
    __syncthreads();
    for (int off = 1; off < NPB; off <<= 1) {
        int v = 0;
        if (t < NPB && t >= off) v = scan_s[t - off];
        __syncthreads();
        if (t < NPB) scan_s[t] += v;
        __syncthreads();
    }
    int i0 = b * NPB;
    if (t < NPB) {
        base_s[t] = lo + scan_s[t] - cnt[t];   // exclusive start of node's run
        int i = i0 + t;
        if (i < n) {
            rowp[i] = base_s[t];
            dis[i] = rsqrtf(1.0f + (float)cnt[t]);  // +1 self-loop
        }
        cnt[t] = 0;  // reuse as cursor
    }
    __syncthreads();
    for (int e = lo + t; e < hi; e += 256) {
        int w = packed[e];
        int dl = w >> 17;
        int pos = base_s[dl] + atomicAdd(&cnt[dl], 1);
        col[pos] = w & 0x1FFFF;
    }
    if (b == nb - 1 && t == 0) rowp[n] = hi;
}

// ---- g = dis_i*(x_i@W1), stored fp16 ----
__global__ void k_gemm1(const float* __restrict__ x, const float* __restrict__ W1,
                        const float* __restrict__ dis, __half* __restrict__ gh, int n) {
    __shared__ float Ws[F_DIM * H_DIM];
    for (int t = threadIdx.x; t < F_DIM * H_DIM; t += blockDim.x) Ws[t] = W1[t];
    __syncthreads();
    int i = blockIdx.x * blockDim.x + threadIdx.x;
    if (i >= n) return;

    float acc[H_DIM];
#pragma unroll
    for (int j = 0; j < H_DIM; j++) acc[j] = 0.0f;

    const float4* xv = (const float4*)(x + (size_t)i * F_DIM);
#pragma unroll 4
    for (int k4 = 0; k4 < F_DIM / 4; k4++) {
        float4 v = xv[k4];
        int k = k4 * 4;
#pragma unroll
        for (int j = 0; j < H_DIM; j++) acc[j] += v.x * Ws[(k + 0) * H_DIM + j];
#pragma unroll
        for (int j = 0; j < H_DIM; j++) acc[j] += v.y * Ws[(k + 1) * H_DIM + j];
#pragma unroll
        for (int j = 0; j < H_DIM; j++) acc[j] += v.z * Ws[(k + 2) * H_DIM + j];
#pragma unroll
        for (int j = 0; j < H_DIM; j++) acc[j] += v.w * Ws[(k + 3) * H_DIM + j];
    }
    float d = dis[i];
    __half2* hp = (__half2*)(gh + ((size_t)i << 4));
#pragma unroll
    for (int p = 0; p < 8; p++)
        hp[p] = __floats2half2_rn(d * acc[2 * p], d * acc[2 * p + 1]);
}

// ---- conv1 per-node register aggregation + relu + W2 -> g2 ----
// 4 lanes/node (lane c holds dims 4c..4c+3), batch-4 edges, NO LDS.
__global__ __launch_bounds__(256) void k_p2n(
        const int* __restrict__ col, const int* __restrict__ rowp,
        const __half* __restrict__ gh, const float* __restrict__ dis,
        const float* __restrict__ b1, const float* __restrict__ W2,
        float* __restrict__ g2, int n) {
    int t = threadIdx.x;
    int i = blockIdx.x * 64 + (t >> 2);
    int c = t & 3;
    if (i >= n) return;
    int lo = rowp[i], hi = rowp[i + 1];

    // self-loop term: dis_i * g_i (dis_src folded into gh)
    h4 us = *(const h4*)(gh + ((size_t)i << 4) + (c << 2));
    float2 s0 = __half22float2(us.a), s1 = __half22float2(us.b);
    float a0 = s0.x, a1 = s0.y, a2 = s1.x, a3 = s1.y;

    for (int base = lo; base < hi; base += 4) {
        int last = hi - 1;
        int e1 = base + 1, e2 = base + 2, e3 = base + 3;
        bool v1 = e1 < hi, v2 = e2 < hi, v3 = e3 < hi;
        int c0 = col[base];
        int c1 = col[v1 ? e1 : last];
        int c2 = col[v2 ? e2 : last];
        int c3 = col[v3 ? e3 : last];
        h4 u0 = *(const h4*)(gh + ((size_t)c0 << 4) + (c << 2));
        h4 u1 = *(const h4*)(gh + ((size_t)c1 << 4) + (c << 2));
        h4 u2 = *(const h4*)(gh + ((size_t)c2 << 4) + (c << 2));
        h4 u3 = *(const h4*)(gh + ((size_t)c3 << 4) + (c << 2));
        float m1 = v1 ? 1.0f : 0.0f, m2 = v2 ? 1.0f : 0.0f, m3 = v3 ? 1.0f : 0.0f;
        float2 f;
        f = __half22float2(u0.a); a0 += f.x; a1 += f.y;
        f = __half22float2(u0.b); a2 += f.x; a3 += f.y;
        f = __half22float2(u1.a); a0 += f.x * m1; a1 += f.y * m1;
        f = __half22float2(u1.b); a2 += f.x * m1; a3 += f.y * m1;
        f = __half22float2(u2.a); a0 += f.x * m2; a1 += f.y * m2;
        f = __half22float2(u2.b); a2 += f.x * m2; a3 += f.y * m2;
        f = __half22float2(u3.a); a0 += f.x * m3; a1 += f.y * m3;
        f = __half22float2(u3.b); a2 += f.x * m3; a3 += f.y * m3;
    }

    float d = dis[i];
    int j0 = c << 2;
    float p = 0.0f;
    p += fmaxf(fmaf(d, a0, b1[j0 + 0]), 0.0f) * W2[j0 + 0];
    p += fmaxf(fmaf(d, a1, b1[j0 + 1]), 0.0f) * W2[j0 + 1];
    p += fmaxf(fmaf(d, a2, b1[j0 + 2]), 0.0f) * W2[j0 + 2];
    p += fmaxf(fmaf(d, a3, b1[j0 + 3]), 0.0f) * W2[j0 + 3];
    p += __shfl_xor(p, 1);
    p += __shfl_xor(p, 2);
    if (c == 0) g2[i] = d * p;
}

// ---- conv2 per-node register aggregation -> out ----
// 1 thread/node, batch-8 scalar gathers, NO LDS.
__global__ __launch_bounds__(256) void k_p3n(
        const int* __restrict__ col, const int* __restrict__ rowp,
        const float* __restrict__ g2, const float* __restrict__ dis,
        const float* __restrict__ b2, float* __restrict__ out, int n) {
    int i = blockIdx.x * 256 + threadIdx.x;
    if (i >= n) return;
    int lo = rowp[i], hi = rowp[i + 1];
    float s = g2[i];  // self-loop
    for (int base = lo; base < hi; base += 8) {
        int idx[8]; float v[8]; bool ok[8];
        int last = hi - 1;
#pragma unroll
        for (int k = 0; k < 8; k++) {
            int e = base + k;
            ok[k] = e < hi;
            idx[k] = col[ok[k] ? e : last];
        }
#pragma unroll
        for (int k = 0; k < 8; k++) v[k] = g2[idx[k]];
#pragma unroll
        for (int k = 0; k < 8; k++) s += ok[k] ? v[k] : 0.0f;
    }
    out[i] = b2[0] + dis[i] * s;
}

extern "C" void kernel_launch(void* const* d_in, const int* in_sizes, int n_in,
                              void* d_out, int out_size, void* d_ws, size_t ws_size,
                              hipStream_t stream) {
    const float* x  = (const float*)d_in[0];
    const int*   ei = (const int*)d_in[1];
    const float* W1 = (const float*)d_in[2];
    const float* b1 = (const float*)d_in[3];
    const float* W2 = (const float*)d_in[4];
    const float* b2 = (const float*)d_in[5];

    const int n = in_sizes[0] / F_DIM;
    const int e = in_sizes[1] / 2;
    const int* src = ei;
    const int* dst = ei + e;
    const int nb = (n + NPB - 1) / NPB;

    // workspace layout (base 256B-aligned)
    char* p = (char*)d_ws;
    float* dis    = (float*)p;  p += sizeof(float) * n;
    float* g2     = (float*)p;  p += sizeof(float) * n;
    __half* gh    = (__half*)p; p += sizeof(__half) * (size_t)n * H_DIM;
    int*   col    = (int*)p;    p += sizeof(int) * (size_t)e;
    int*   rowp   = (int*)p;    p += sizeof(int) * (n + 1);
    int*   packed = (int*)p;    p += sizeof(int) * (size_t)e;
    int*   blk_cnt= (int*)p;    p += sizeof(int) * (size_t)nb * NBLK1;
    int*   starts = (int*)p;    p += sizeof(int) * (nb + 1);

    float* out = (float*)d_out;
    const int B = 256;

    k_count<<<NBLK1, T1, 0, stream>>>(dst, e, blk_cnt, nb);
    k_scan<<<1, T1, 0, stream>>>(blk_cnt, starts, nb);
    k_bases<<<nb, NBLK1, 0, stream>>>(blk_cnt, starts);
    k_place<<<NBLK1, T1, 0, stream>>>(src, dst, e, blk_cnt, packed, nb);
    k_sort<<<nb, B, 0, stream>>>(packed, starts, col, rowp, dis, n, nb);
    k_gemm1<<<(n + B - 1) / B, B, 0, stream>>>(x, W1, dis, gh, n);
    k_p2n<<<(n + 63) / 64, B, 0, stream>>>(col, rowp, gh, dis, b1, W2, g2, n);
    k_p3n<<<(n + B - 1) / B, B, 0, stream>>>(col, rowp, g2, dis, b2, out, n);
}

// Round 7
// 258.172 us; speedup vs baseline: 2.3677x; 1.0083x over previous
//
#include <hip/hip_runtime.h>
#include <hip/hip_fp16.h>

#define F_DIM 128
#define H_DIM 16
#define NPB 128          // nodes per bucket (power of 2, dst>>7)
#define NPB_SHIFT 7
#define NB_MAX 1024      // max buckets supported (n <= 131072)
#define NBLK1 128        // blocks in bucketing passes (segment owners)
#define T1 1024          // threads in bucketing passes
#define SENT (-1)        // sentinel for pad slots

struct __align__(8) h4 { __half2 a, b; };  // 4 halves, one dwordx2

// ---------------- phase 1a: per-block per-bucket edge counts ----------------
__global__ void k_count(const int* __restrict__ dst, int e, int* __restrict__ blk_cnt, int nb) {
    __shared__ int hist[NB_MAX];
    for (int t = threadIdx.x; t < nb; t += T1) hist[t] = 0;
    __syncthreads();
    int chunk = (e + NBLK1 - 1) / NBLK1;
    int lo = blockIdx.x * chunk;
    int hi = min(e, lo + chunk);
    for (int i = lo + threadIdx.x; i < hi; i += T1)
        atomicAdd(&hist[dst[i] >> NPB_SHIFT], 1);
    __syncthreads();
    for (int b = threadIdx.x; b < nb; b += T1)
        blk_cnt[b * NBLK1 + blockIdx.x] = hist[b];
}

// ---------------- phase 1b-1: per-bucket PADDED totals (parallel) ----------------
__global__ void k_rowsum(const int* __restrict__ blk_cnt, int* __restrict__ tot) {
    int b = blockIdx.x, t = threadIdx.x;  // 64 threads
    const int* row = blk_cnt + (size_t)b * NBLK1;
    int c0 = row[t], c1 = row[t + 64];
    int s = ((c0 + 15) & ~15) + ((c1 + 15) & ~15);
#pragma unroll
    for (int off = 32; off > 0; off >>= 1) s += __shfl_down(s, off);
    if (t == 0) tot[b] = s;
}

// ---------------- phase 1b-2: exclusive scan of padded totals ----------------
__global__ void k_scan2(const int* __restrict__ tot, int* __restrict__ starts, int nb) {
    __shared__ int s[1024];
    int t = threadIdx.x;
    s[t] = (t < nb) ? tot[t] : 0;
    __syncthreads();
    for (int off = 1; off < 1024; off <<= 1) {
        int u = (t >= off) ? s[t - off] : 0;
        __syncthreads();
        s[t] += u;
        __syncthreads();
    }
    if (t == 0) starts[0] = 0;
    if (t < nb) starts[t + 1] = s[t];
}

// ---------------- phase 1c: per-(bucket,block) PADDED bases, in place ----------------
__global__ void k_bases(int* __restrict__ blk_cnt, const int* __restrict__ starts) {
    __shared__ int s[NBLK1];
    int row = blockIdx.x;
    int t = threadIdx.x;  // 128 threads
    int v = (blk_cnt[row * NBLK1 + t] + 15) & ~15;  // padded count
    s[t] = v;
    __syncthreads();
    for (int off = 1; off < NBLK1; off <<= 1) {
        int u = (t >= off) ? s[t - off] : 0;
        __syncthreads();
        s[t] += u;
        __syncthreads();
    }
    blk_cnt[row * NBLK1 + t] = starts[row] + s[t] - v;  // 64B-aligned base
}

// ------- phase 1d: place edges into OWNED 64B-aligned segments + sentinel pads -------
__global__ void k_place(const int* __restrict__ src, const int* __restrict__ dst, int e,
                        const int* __restrict__ bases, int* __restrict__ packed, int nb) {
    __shared__ int lcur[NB_MAX];
    for (int t = threadIdx.x; t < nb; t += T1) lcur[t] = 0;
    __syncthreads();
    int chunk = (e + NBLK1 - 1) / NBLK1;
    int lo = blockIdx.x * chunk;
    int hi = min(e, lo + chunk);
    for (int i = lo + threadIdx.x; i < hi; i += T1) {
        int d = dst[i];
        int b = d >> NPB_SHIFT;
        int dl = d & (NPB - 1);
        int pos = bases[b * NBLK1 + blockIdx.x] + atomicAdd(&lcur[b], 1);
        packed[pos] = src[i] | (dl << 17);
    }
    __syncthreads();
    // fill this block's pad slots with sentinel
    for (int b = threadIdx.x; b < nb; b += T1) {
        int c = lcur[b];
        int base = bases[b * NBLK1 + blockIdx.x];
        int ce = (c + 15) & ~15;
        for (int k = c; k < ce; k++) packed[base + k] = SENT;
    }
}

// ---- phase 2: within-bucket counting sort by dst -> CSR (col, rowp, rowe) + dis ----
__global__ __launch_bounds__(256) void k_sort(
        const int* __restrict__ packed, const int* __restrict__ starts,
        int* __restrict__ col, int* __restrict__ rowp, int* __restrict__ rowe,
        float* __restrict__ dis, int n) {
    __shared__ int cnt[NPB];
    __shared__ int scan_s[NPB];
    __shared__ int base_s[NPB];
    int b = blockIdx.x, t = threadIdx.x;
    if (t < NPB) cnt[t] = 0;
    __syncthreads();
    int lo = starts[b], hi = starts[b + 1];
    for (int e = lo + t; e < hi; e += 256) {
        int w = packed[e];
        if (w != SENT) atomicAdd(&cnt[w >> 17], 1);
    }
    __syncthreads();
    if (t < NPB) scan_s[t] = cnt[t];
    __syncthreads();
    for (int off = 1; off < NPB; off <<= 1) {
        int v = 0;
        if (t < NPB && t >= off) v = scan_s[t - off];
        __syncthreads();
        if (t < NPB) scan_s[t] += v;
        __syncthreads();
    }
    int i0 = b * NPB;
    if (t < NPB) {
        int c = cnt[t];
        base_s[t] = lo + scan_s[t] - c;   // exclusive start of node's run
        int i = i0 + t;
        if (i < n) {
            rowp[i] = base_s[t];
            rowe[i] = base_s[t] + c;
            dis[i] = rsqrtf(1.0f + (float)c);  // +1 self-loop
        }
        cnt[t] = 0;  // reuse as cursor
    }
    __syncthreads();
    for (int e = lo + t; e < hi; e += 256) {
        int w = packed[e];
        if (w == SENT) continue;
        int dl = w >> 17;
        int pos = base_s[dl] + atomicAdd(&cnt[dl], 1);
        col[pos] = w & 0x1FFFF;
    }
}

// ---- g = dis_i*(x_i@W1), stored fp16 ----
__global__ void k_gemm1(const float* __restrict__ x, const float* __restrict__ W1,
                        const float* __restrict__ dis, __half* __restrict__ gh, int n) {
    __shared__ float Ws[F_DIM * H_DIM];
    for (int t = threadIdx.x; t < F_DIM * H_DIM; t += blockDim.x) Ws[t] = W1[t];
    __syncthreads();
    int i = blockIdx.x * blockDim.x + threadIdx.x;
    if (i >= n) return;

    float acc[H_DIM];
#pragma unroll
    for (int j = 0; j < H_DIM; j++) acc[j] = 0.0f;

    const float4* xv = (const float4*)(x + (size_t)i * F_DIM);
#pragma unroll 4
    for (int k4 = 0; k4 < F_DIM / 4; k4++) {
        float4 v = xv[k4];
        int k = k4 * 4;
#pragma unroll
        for (int j = 0; j < H_DIM; j++) acc[j] += v.x * Ws[(k + 0) * H_DIM + j];
#pragma unroll
        for (int j = 0; j < H_DIM; j++) acc[j] += v.y * Ws[(k + 1) * H_DIM + j];
#pragma unroll
        for (int j = 0; j < H_DIM; j++) acc[j] += v.z * Ws[(k + 2) * H_DIM + j];
#pragma unroll
        for (int j = 0; j < H_DIM; j++) acc[j] += v.w * Ws[(k + 3) * H_DIM + j];
    }
    float d = dis[i];
    __half2* hp = (__half2*)(gh + ((size_t)i << 4));
#pragma unroll
    for (int p = 0; p < 8; p++)
        hp[p] = __floats2half2_rn(d * acc[2 * p], d * acc[2 * p + 1]);
}

// ---- conv1 per-node register aggregation + relu + W2 -> g2 ----
// 4 lanes/node (lane c holds dims 4c..4c+3), batch-8 edges, NO LDS.
__global__ __launch_bounds__(256) void k_p2n(
        const int* __restrict__ col, const int* __restrict__ rowp,
        const int* __restrict__ rowe, const __half* __restrict__ gh,
        const float* __restrict__ dis, const float* __restrict__ b1,
        const float* __restrict__ W2, float* __restrict__ g2, int n) {
    int t = threadIdx.x;
    int i = blockIdx.x * 64 + (t >> 2);
    int c = t & 3;
    if (i >= n) return;
    int lo = rowp[i], hi = rowe[i];

    // self-loop term: dis_i * g_i (dis_src folded into gh)
    h4 us = *(const h4*)(gh + ((size_t)i << 4) + (c << 2));
    float2 s0 = __half22float2(us.a), s1 = __half22float2(us.b);
    float a0 = s0.x, a1 = s0.y, a2 = s1.x, a3 = s1.y;

    for (int base = lo; base < hi; base += 8) {
        int last = hi - 1;
        int idx[8]; h4 u[8]; float m[8];
#pragma unroll
        for (int k = 0; k < 8; k++) {
            int e = base + k;
            bool v = e < hi;
            idx[k] = col[v ? e : last];
            m[k] = v ? 1.0f : 0.0f;
        }
#pragma unroll
        for (int k = 0; k < 8; k++)
            u[k] = *(const h4*)(gh + ((size_t)idx[k] << 4) + (c << 2));
#pragma unroll
        for (int k = 0; k < 8; k++) {
            float2 f0 = __half22float2(u[k].a);
            float2 f1 = __half22float2(u[k].b);
            a0 += f0.x * m[k]; a1 += f0.y * m[k];
            a2 += f1.x * m[k]; a3 += f1.y * m[k];
        }
    }

    float d = dis[i];
    int j0 = c << 2;
    float p = 0.0f;
    p += fmaxf(fmaf(d, a0, b1[j0 + 0]), 0.0f) * W2[j0 + 0];
    p += fmaxf(fmaf(d, a1, b1[j0 + 1]), 0.0f) * W2[j0 + 1];
    p += fmaxf(fmaf(d, a2, b1[j0 + 2]), 0.0f) * W2[j0 + 2];
    p += fmaxf(fmaf(d, a3, b1[j0 + 3]), 0.0f) * W2[j0 + 3];
    p += __shfl_xor(p, 1);
    p += __shfl_xor(p, 2);
    if (c == 0) g2[i] = d * p;
}

// ---- conv2 per-node register aggregation -> out ----
__global__ __launch_bounds__(256) void k_p3n(
        const int* __restrict__ col, const int* __restrict__ rowp,
        const int* __restrict__ rowe, const float* __restrict__ g2,
        const float* __restrict__ dis, const float* __restrict__ b2,
        float* __restrict__ out, int n) {
    int i = blockIdx.x * 256 + threadIdx.x;
    if (i >= n) return;
    int lo = rowp[i], hi = rowe[i];
    float s = g2[i];  // self-loop
    for (int base = lo; base < hi; base += 8) {
        int idx[8]; float v[8]; bool ok[8];
        int last = hi - 1;
#pragma unroll
        for (int k = 0; k < 8; k++) {
            int e = base + k;
            ok[k] = e < hi;
            idx[k] = col[ok[k] ? e : last];
        }
#pragma unroll
        for (int k = 0; k < 8; k++) v[k] = g2[idx[k]];
#pragma unroll
        for (int k = 0; k < 8; k++) s += ok[k] ? v[k] : 0.0f;
    }
    out[i] = b2[0] + dis[i] * s;
}

extern "C" void kernel_launch(void* const* d_in, const int* in_sizes, int n_in,
                              void* d_out, int out_size, void* d_ws, size_t ws_size,
                              hipStream_t stream) {
    const float* x  = (const float*)d_in[0];
    const int*   ei = (const int*)d_in[1];
    const float* W1 = (const float*)d_in[2];
    const float* b1 = (const float*)d_in[3];
    const float* W2 = (const float*)d_in[4];
    const float* b2 = (const float*)d_in[5];

    const int n = in_sizes[0] / F_DIM;
    const int e = in_sizes[1] / 2;
    const int* src = ei;
    const int* dst = ei + e;
    const int nb = (n + NPB - 1) / NPB;
    // worst-case padded edge-array length (each (bucket,block) pads up to 15 ints)
    const size_t ep = (size_t)e + (size_t)nb * NBLK1 * 16;

    // workspace layout, every region rounded to 256 B
    char* p = (char*)d_ws;
    auto take = [&](size_t bytes) { char* r = p; p += (bytes + 255) & ~(size_t)255; return r; };
    float* dis    = (float*)take(sizeof(float) * n);
    float* g2     = (float*)take(sizeof(float) * n);
    __half* gh    = (__half*)take(sizeof(__half) * (size_t)n * H_DIM);
    int*   col    = (int*)take(sizeof(int) * ep);
    int*   packed = (int*)take(sizeof(int) * ep);
    int*   rowp   = (int*)take(sizeof(int) * n);
    int*   rowe   = (int*)take(sizeof(int) * n);
    int*   blk_cnt= (int*)take(sizeof(int) * (size_t)nb * NBLK1);
    int*   tot    = (int*)take(sizeof(int) * nb);
    int*   starts = (int*)take(sizeof(int) * (nb + 1));

    float* out = (float*)d_out;
    const int B = 256;

    k_count<<<NBLK1, T1, 0, stream>>>(dst, e, blk_cnt, nb);
    k_rowsum<<<nb, 64, 0, stream>>>(blk_cnt, tot);
    k_scan2<<<1, 1024, 0, stream>>>(tot, starts, nb);
    k_bases<<<nb, NBLK1, 0, stream>>>(blk_cnt, starts);
    k_place<<<NBLK1, T1, 0, stream>>>(src, dst, e, blk_cnt, packed, nb);
    k_sort<<<nb, B, 0, stream>>>(packed, starts, col, rowp, rowe, dis, n);
    k_gemm1<<<(n + B - 1) / B, B, 0, stream>>>(x, W1, dis, gh, n);
    k_p2n<<<(n + 63) / 64, B, 0, stream>>>(col, rowp, rowe, gh, dis, b1, W2, g2, n);
    k_p3n<<<(n + B - 1) / B, B, 0, stream>>>(col, rowp, rowe, g2, dis, b2, out, n);
}

// Round 8
// 233.687 us; speedup vs baseline: 2.6157x; 1.1048x over previous
//
#include <hip/hip_runtime.h>
#include <hip/hip_fp16.h>

#define F_DIM 128
#define H_DIM 16
#define NPB 128          // nodes per bucket (power of 2, dst>>7)
#define NPB_SHIFT 7
#define NB_MAX 1024      // max buckets supported (n <= 131072)
#define NBLK1 256        // blocks in bucketing passes
#define T1 1024          // threads in bucketing passes

struct __align__(8) h4 { __half2 a, b; };  // 4 halves, one dwordx2

// ---------------- phase 1a: per-block per-bucket edge counts ----------------
__global__ void k_count(const int* __restrict__ dst, int e, int* __restrict__ blk_cnt, int nb) {
    __shared__ int hist[NB_MAX];
    for (int t = threadIdx.x; t < nb; t += T1) hist[t] = 0;
    __syncthreads();
    int chunk = (e + NBLK1 - 1) / NBLK1;
    int lo = blockIdx.x * chunk;
    int hi = min(e, lo + chunk);
    for (int i = lo + threadIdx.x; i < hi; i += T1)
        atomicAdd(&hist[dst[i] >> NPB_SHIFT], 1);
    __syncthreads();
    for (int b = threadIdx.x; b < nb; b += T1)
        blk_cnt[b * NBLK1 + blockIdx.x] = hist[b];
}

// ---------------- phase 1b-1: per-bucket totals (parallel) ----------------
__global__ void k_rowsum(const int* __restrict__ blk_cnt, int* __restrict__ tot) {
    int b = blockIdx.x, t = threadIdx.x;  // 64 threads
    const int* row = blk_cnt + (size_t)b * NBLK1;
    int s = row[t] + row[t + 64] + row[t + 128] + row[t + 192];
#pragma unroll
    for (int off = 32; off > 0; off >>= 1) s += __shfl_down(s, off);
    if (t == 0) tot[b] = s;
}

// ---------------- phase 1b-2: exclusive scan of totals ----------------
__global__ void k_scan2(const int* __restrict__ tot, int* __restrict__ starts, int nb) {
    __shared__ int s[1024];
    int t = threadIdx.x;
    s[t] = (t < nb) ? tot[t] : 0;
    __syncthreads();
    for (int off = 1; off < 1024; off <<= 1) {
        int u = (t >= off) ? s[t - off] : 0;
        __syncthreads();
        s[t] += u;
        __syncthreads();
    }
    if (t == 0) starts[0] = 0;
    if (t < nb) starts[t + 1] = s[t];
}

// ---------------- phase 1c: per-(bucket,block) bases, in place ----------------
__global__ void k_bases(int* __restrict__ blk_cnt, const int* __restrict__ starts) {
    __shared__ int s[NBLK1];
    int row = blockIdx.x;
    int t = threadIdx.x;  // NBLK1 threads
    int v = blk_cnt[row * NBLK1 + t];
    s[t] = v;
    __syncthreads();
    for (int off = 1; off < NBLK1; off <<= 1) {
        int u = (t >= off) ? s[t - off] : 0;
        __syncthreads();
        s[t] += u;
        __syncthreads();
    }
    blk_cnt[row * NBLK1 + t] = starts[row] + s[t] - v;
}

// ------- phase 1d: tile-sorted placement with COALESCED writes -------
// Per 1024-edge tile: LDS histogram by bucket -> shfl-based exclusive scan ->
// stage sorted by bucket -> write (same-bucket edges in adjacent lanes =>
// full-line coalesced stores; no partial-line writeback amplification).
__global__ __launch_bounds__(1024) void k_place(
        const int* __restrict__ src, const int* __restrict__ dst, int e,
        const int* __restrict__ bases, int* __restrict__ packed, int nb) {
    __shared__ int tcnt[NB_MAX];
    __shared__ int toff[NB_MAX];   // exclusive offsets within tile
    __shared__ int gcur[NB_MAX];   // running cursor within block's segment
    __shared__ int stage[T1];
    __shared__ short sbkt[T1];
    __shared__ int wsum[16];
    __shared__ int wpre[16];
    int t = threadIdx.x;
    int lane = t & 63, wv = t >> 6;
    for (int b = t; b < nb; b += T1) gcur[b] = 0;
    int chunk = (e + NBLK1 - 1) / NBLK1;
    int lo = blockIdx.x * chunk;
    int hi = min(e, lo + chunk);

    for (int tile = lo; tile < hi; tile += T1) {
        for (int b = t; b < nb; b += T1) tcnt[b] = 0;
        __syncthreads();
        // classify
        int i = tile + t;
        int b = -1, val = 0, r = 0;
        if (i < hi) {
            int d = dst[i];
            b = d >> NPB_SHIFT;
            val = src[i] | ((d & (NPB - 1)) << 17);
            r = atomicAdd(&tcnt[b], 1);
        }
        __syncthreads();
        // exclusive scan of tcnt[0..1023]: wave shfl-scan + 16-partial scan
        int v = tcnt[t];
        int sc = v;
#pragma unroll
        for (int off = 1; off < 64; off <<= 1) {
            int u = __shfl_up(sc, off);
            if (lane >= off) sc += u;
        }
        if (lane == 63) wsum[wv] = sc;
        __syncthreads();
        if (t < 16) {
            int s = wsum[t];
#pragma unroll
            for (int off = 1; off < 16; off <<= 1) {
                int u = __shfl_up(s, off);
                if (lane >= off) s += u;
            }
            wpre[t] = s;  // inclusive over wave sums
        }
        __syncthreads();
        toff[t] = sc - v + (wv ? wpre[wv - 1] : 0);  // exclusive offset
        __syncthreads();
        // stage sorted by bucket
        if (b >= 0) {
            int slot = toff[b] + r;
            stage[slot] = val;
            sbkt[slot] = (short)b;
        }
        __syncthreads();
        // coalesced write
        int tilecnt = min(hi - tile, T1);
        if (t < tilecnt) {
            int bb = sbkt[t];
            int pos = bases[bb * NBLK1 + blockIdx.x] + gcur[bb] + (t - toff[bb]);
            packed[pos] = stage[t];
        }
        __syncthreads();
        // advance cursors
        for (int bb = t; bb < nb; bb += T1) gcur[bb] += tcnt[bb];
        __syncthreads();
    }
}

// ---- phase 2: within-bucket counting sort by dst -> CSR (col, rowp, rowe) + dis ----
__global__ __launch_bounds__(256) void k_sort(
        const int* __restrict__ packed, const int* __restrict__ starts,
        int* __restrict__ col, int* __restrict__ rowp, int* __restrict__ rowe,
        float* __restrict__ dis, int n) {
    __shared__ int cnt[NPB];
    __shared__ int scan_s[NPB];
    __shared__ int base_s[NPB];
    int b = blockIdx.x, t = threadIdx.x;
    if (t < NPB) cnt[t] = 0;
    __syncthreads();
    int lo = starts[b], hi = starts[b + 1];
    for (int e = lo + t; e < hi; e += 256)
        atomicAdd(&cnt[packed[e] >> 17], 1);
    __syncthreads();
    if (t < NPB) scan_s[t] = cnt[t];
    __syncthreads();
    for (int off = 1; off < NPB; off <<= 1) {
        int v = 0;
        if (t < NPB && t >= off) v = scan_s[t - off];
        __syncthreads();
        if (t < NPB) scan_s[t] += v;
        __syncthreads();
    }
    int i0 = b * NPB;
    if (t < NPB) {
        int c = cnt[t];
        base_s[t] = lo + scan_s[t] - c;
        int i = i0 + t;
        if (i < n) {
            rowp[i] = base_s[t];
            rowe[i] = base_s[t] + c;
            dis[i] = rsqrtf(1.0f + (float)c);  // +1 self-loop
        }
        cnt[t] = 0;  // reuse as cursor
    }
    __syncthreads();
    for (int e = lo + t; e < hi; e += 256) {
        int w = packed[e];
        int dl = w >> 17;
        int pos = base_s[dl] + atomicAdd(&cnt[dl], 1);
        col[pos] = w & 0x1FFFF;
    }
}

// ---- g = dis_i*(x_i@W1), stored fp16 ----
__global__ void k_gemm1(const float* __restrict__ x, const float* __restrict__ W1,
                        const float* __restrict__ dis, __half* __restrict__ gh, int n) {
    __shared__ float Ws[F_DIM * H_DIM];
    for (int t = threadIdx.x; t < F_DIM * H_DIM; t += blockDim.x) Ws[t] = W1[t];
    __syncthreads();
    int i = blockIdx.x * blockDim.x + threadIdx.x;
    if (i >= n) return;

    float acc[H_DIM];
#pragma unroll
    for (int j = 0; j < H_DIM; j++) acc[j] = 0.0f;

    const float4* xv = (const float4*)(x + (size_t)i * F_DIM);
#pragma unroll 4
    for (int k4 = 0; k4 < F_DIM / 4; k4++) {
        float4 v = xv[k4];
        int k = k4 * 4;
#pragma unroll
        for (int j = 0; j < H_DIM; j++) acc[j] += v.x * Ws[(k + 0) * H_DIM + j];
#pragma unroll
        for (int j = 0; j < H_DIM; j++) acc[j] += v.y * Ws[(k + 1) * H_DIM + j];
#pragma unroll
        for (int j = 0; j < H_DIM; j++) acc[j] += v.z * Ws[(k + 2) * H_DIM + j];
#pragma unroll
        for (int j = 0; j < H_DIM; j++) acc[j] += v.w * Ws[(k + 3) * H_DIM + j];
    }
    float d = dis[i];
    __half2* hp = (__half2*)(gh + ((size_t)i << 4));
#pragma unroll
    for (int p = 0; p < 8; p++)
        hp[p] = __floats2half2_rn(d * acc[2 * p], d * acc[2 * p + 1]);
}

// ---- conv1 per-node register aggregation + relu + W2 -> g2 ----
__global__ __launch_bounds__(256) void k_p2n(
        const int* __restrict__ col, const int* __restrict__ rowp,
        const int* __restrict__ rowe, const __half* __restrict__ gh,
        const float* __restrict__ dis, const float* __restrict__ b1,
        const float* __restrict__ W2, float* __restrict__ g2, int n) {
    int t = threadIdx.x;
    int i = blockIdx.x * 64 + (t >> 2);
    int c = t & 3;
    if (i >= n) return;
    int lo = rowp[i], hi = rowe[i];

    h4 us = *(const h4*)(gh + ((size_t)i << 4) + (c << 2));
    float2 s0 = __half22float2(us.a), s1 = __half22float2(us.b);
    float a0 = s0.x, a1 = s0.y, a2 = s1.x, a3 = s1.y;

    for (int base = lo; base < hi; base += 8) {
        int last = hi - 1;
        int idx[8]; h4 u[8]; float m[8];
#pragma unroll
        for (int k = 0; k < 8; k++) {
            int e = base + k;
            bool v = e < hi;
            idx[k] = col[v ? e : last];
            m[k] = v ? 1.0f : 0.0f;
        }
#pragma unroll
        for (int k = 0; k < 8; k++)
            u[k] = *(const h4*)(gh + ((size_t)idx[k] << 4) + (c << 2));
#pragma unroll
        for (int k = 0; k < 8; k++) {
            float2 f0 = __half22float2(u[k].a);
            float2 f1 = __half22float2(u[k].b);
            a0 += f0.x * m[k]; a1 += f0.y * m[k];
            a2 += f1.x * m[k]; a3 += f1.y * m[k];
        }
    }

    float d = dis[i];
    int j0 = c << 2;
    float p = 0.0f;
    p += fmaxf(fmaf(d, a0, b1[j0 + 0]), 0.0f) * W2[j0 + 0];
    p += fmaxf(fmaf(d, a1, b1[j0 + 1]), 0.0f) * W2[j0 + 1];
    p += fmaxf(fmaf(d, a2, b1[j0 + 2]), 0.0f) * W2[j0 + 2];
    p += fmaxf(fmaf(d, a3, b1[j0 + 3]), 0.0f) * W2[j0 + 3];
    p += __shfl_xor(p, 1);
    p += __shfl_xor(p, 2);
    if (c == 0) g2[i] = d * p;
}

// ---- conv2 per-node register aggregation -> out ----
__global__ __launch_bounds__(256) void k_p3n(
        const int* __restrict__ col, const int* __restrict__ rowp,
        const int* __restrict__ rowe, const float* __restrict__ g2,
        const float* __restrict__ dis, const float* __restrict__ b2,
        float* __restrict__ out, int n) {
    int i = blockIdx.x * 256 + threadIdx.x;
    if (i >= n) return;
    int lo = rowp[i], hi = rowe[i];
    float s = g2[i];
    for (int base = lo; base < hi; base += 8) {
        int idx[8]; float v[8]; bool ok[8];
        int last = hi - 1;
#pragma unroll
        for (int k = 0; k < 8; k++) {
            int e = base + k;
            ok[k] = e < hi;
            idx[k] = col[ok[k] ? e : last];
        }
#pragma unroll
        for (int k = 0; k < 8; k++) v[k] = g2[idx[k]];
#pragma unroll
        for (int k = 0; k < 8; k++) s += ok[k] ? v[k] : 0.0f;
    }
    out[i] = b2[0] + dis[i] * s;
}

extern "C" void kernel_launch(void* const* d_in, const int* in_sizes, int n_in,
                              void* d_out, int out_size, void* d_ws, size_t ws_size,
                              hipStream_t stream) {
    const float* x  = (const float*)d_in[0];
    const int*   ei = (const int*)d_in[1];
    const float* W1 = (const float*)d_in[2];
    const float* b1 = (const float*)d_in[3];
    const float* W2 = (const float*)d_in[4];
    const float* b2 = (const float*)d_in[5];

    const int n = in_sizes[0] / F_DIM;
    const int e = in_sizes[1] / 2;
    const int* src = ei;
    const int* dst = ei + e;
    const int nb = (n + NPB - 1) / NPB;

    // workspace layout, regions rounded to 256 B
    char* p = (char*)d_ws;
    auto take = [&](size_t bytes) { char* r = p; p += (bytes + 255) & ~(size_t)255; return r; };
    float* dis    = (float*)take(sizeof(float) * n);
    float* g2     = (float*)take(sizeof(float) * n);
    __half* gh    = (__half*)take(sizeof(__half) * (size_t)n * H_DIM);
    int*   col    = (int*)take(sizeof(int) * (size_t)e);
    int*   packed = (int*)take(sizeof(int) * (size_t)e);
    int*   rowp   = (int*)take(sizeof(int) * n);
    int*   rowe   = (int*)take(sizeof(int) * n);
    int*   blk_cnt= (int*)take(sizeof(int) * (size_t)nb * NBLK1);
    int*   tot    = (int*)take(sizeof(int) * nb);
    int*   starts = (int*)take(sizeof(int) * (nb + 1));

    float* out = (float*)d_out;
    const int B = 256;

    k_count<<<NBLK1, T1, 0, stream>>>(dst, e, blk_cnt, nb);
    k_rowsum<<<nb, 64, 0, stream>>>(blk_cnt, tot);
    k_scan2<<<1, 1024, 0, stream>>>(tot, starts, nb);
    k_bases<<<nb, NBLK1, 0, stream>>>(blk_cnt, starts);
    k_place<<<NBLK1, T1, 0, stream>>>(src, dst, e, blk_cnt, packed, nb);
    k_sort<<<nb, B, 0, stream>>>(packed, starts, col, rowp, rowe, dis, n);
    k_gemm1<<<(n + B - 1) / B, B, 0, stream>>>(x, W1, dis, gh, n);
    k_p2n<<<(n + 63) / 64, B, 0, stream>>>(col, rowp, rowe, gh, dis, b1, W2, g2, n);
    k_p3n<<<(n + B - 1) / B, B, 0, stream>>>(col, rowp, rowe, g2, dis, b2, out, n);
}